// Round 4
// baseline (662.371 us; speedup 1.0000x reference)
//
#include <hip/hip_runtime.h>
#include <hip/hip_bf16.h>

#define BB 8
#define NN 2048
#define MM 2048
#define FF 64
#define INF __builtin_inff()

typedef __hip_bfloat16 bf16;

// pack two f32 -> bf16x2 dword (RNE), a in low half
__device__ __forceinline__ unsigned pk_bf16x2(float a, float b) {
  union { __hip_bfloat162 h; unsigned u; } cv;
  cv.h.x = __float2bfloat16(a);
  cv.h.y = __float2bfloat16(b);
  return cv.u;
}

// ---------------- row norms: x2[r] = sum_k x[r][k]^2 ----------------
__global__ void norms_k(const float* __restrict__ a, float* __restrict__ o, int rows) {
  int r = blockIdx.x * 256 + threadIdx.x;
  if (r >= rows) return;
  const float4* p = (const float4*)(a + (size_t)r * FF);
  float s = 0.f;
#pragma unroll
  for (int q = 0; q < FF / 4; ++q) {
    float4 v = p[q];
    s = fmaf(v.x, v.x, fmaf(v.y, v.y, fmaf(v.z, v.z, fmaf(v.w, v.w, s))));
  }
  o[r] = s;
}

// ---------------- INF pad (4KB: 256 lanes x 16B) ----------------
__global__ void fillinf_k(unsigned* __restrict__ p) {
  p[blockIdx.x * 256 + threadIdx.x] = 0x7F807F80u;  // bf16 +INF pair
}

// ---------------- dist tile kernel (unchanged; verified round 2) ----------------
// 64x64 (i,j) tile per WG; fp32 dot via LDS; writes dist COLUMN-MAJOR bf16:
// dist[b][col][row], col stride NN.
__global__ __launch_bounds__(256) void dist_k(const float* __restrict__ X,
                                              const float* __restrict__ Y,
                                              const float* __restrict__ x2,
                                              const float* __restrict__ y2,
                                              bf16* __restrict__ dist) {
  __shared__ float xs[64][68];   // x tile row-major; reused as staged dist tile
  __shared__ float ysT[64][68];  // y tile transposed: ysT[k][j]
  const int b = blockIdx.z, i0 = blockIdx.y * 64, j0 = blockIdx.x * 64;
  const int tid = threadIdx.x, tx = tid & 15, ty = tid >> 4;
  const float* Xb = X + ((size_t)b * NN + i0) * FF;
  const float* Yb = Y + ((size_t)b * MM + j0) * FF;
#pragma unroll
  for (int rep = 0; rep < 4; ++rep) {
    int row = rep * 16 + ty;
    float4 vx = *(const float4*)(Xb + row * FF + tx * 4);
    *(float4*)&xs[row][tx * 4] = vx;
    float4 vy = *(const float4*)(Yb + row * FF + tx * 4);
    ysT[tx * 4 + 0][row] = vy.x;
    ysT[tx * 4 + 1][row] = vy.y;
    ysT[tx * 4 + 2][row] = vy.z;
    ysT[tx * 4 + 3][row] = vy.w;
  }
  __syncthreads();

  const int il0 = ty * 4, jl0 = tx * 4;
  float c[4][4] = {};
#pragma unroll
  for (int k = 0; k < FF; ++k) {
    float a0 = xs[il0 + 0][k], a1 = xs[il0 + 1][k], a2 = xs[il0 + 2][k], a3 = xs[il0 + 3][k];
    float4 bv = *(const float4*)&ysT[k][jl0];
    c[0][0] = fmaf(a0, bv.x, c[0][0]); c[0][1] = fmaf(a0, bv.y, c[0][1]);
    c[0][2] = fmaf(a0, bv.z, c[0][2]); c[0][3] = fmaf(a0, bv.w, c[0][3]);
    c[1][0] = fmaf(a1, bv.x, c[1][0]); c[1][1] = fmaf(a1, bv.y, c[1][1]);
    c[1][2] = fmaf(a1, bv.z, c[1][2]); c[1][3] = fmaf(a1, bv.w, c[1][3]);
    c[2][0] = fmaf(a2, bv.x, c[2][0]); c[2][1] = fmaf(a2, bv.y, c[2][1]);
    c[2][2] = fmaf(a2, bv.z, c[2][2]); c[2][3] = fmaf(a2, bv.w, c[2][3]);
    c[3][0] = fmaf(a3, bv.x, c[3][0]); c[3][1] = fmaf(a3, bv.y, c[3][1]);
    c[3][2] = fmaf(a3, bv.z, c[3][2]); c[3][3] = fmaf(a3, bv.w, c[3][3]);
  }

  float x2v[4], y2v[4];
#pragma unroll
  for (int p = 0; p < 4; ++p) x2v[p] = x2[b * NN + i0 + il0 + p];
#pragma unroll
  for (int q = 0; q < 4; ++q) y2v[q] = y2[b * MM + j0 + jl0 + q];
  __syncthreads();  // all xs/ysT dot-reads done; safe to overwrite xs
#pragma unroll
  for (int p = 0; p < 4; ++p) {
    float4 r;
    r.x = sqrtf(fmaxf(x2v[p] + y2v[0] - 2.f * c[p][0], 0.f));
    r.y = sqrtf(fmaxf(x2v[p] + y2v[1] - 2.f * c[p][1], 0.f));
    r.z = sqrtf(fmaxf(x2v[p] + y2v[2] - 2.f * c[p][2], 0.f));
    r.w = sqrtf(fmaxf(x2v[p] + y2v[3] - 2.f * c[p][3], 0.f));
    *(float4*)&xs[il0 + p][jl0] = r;
  }
  __syncthreads();

  // transposed write-out: per column 4 quarter-parts -> 128B contiguous
  const int cl = tid >> 2, part = tid & 3;
  unsigned w8[8];
#pragma unroll
  for (int m = 0; m < 8; ++m) {
    int r0 = part * 16 + m * 2;
    w8[m] = pk_bf16x2(xs[r0][cl], xs[r0 + 1][cl]);
  }
  bf16* dst = dist + ((size_t)b * MM + (j0 + cl)) * NN + i0 + part * 16;
  *(uint4*)dst = make_uint4(w8[0], w8[1], w8[2], w8[3]);
  *(uint4*)(dst + 8) = make_uint4(w8[4], w8[5], w8[6], w8[7]);
}

// ---------------- DP: 4-wave supertick systolic ----------------
// One 256-thread WG per batch. Lane L owns rows [8L, 8L+8); supertick t: lane L
// processes cols 4(t-L)..+3. Neighbor bottoms via double-buffered LDS float4,
// one raw s_barrier per supertick (lgkmcnt drained; vmcnt NEVER drained -> the
// 4-deep dist prefetch stays in flight across barriers). OOB cols redirect to
// an INF pad placed after the dist array.

// one column: 8 rows. QV holds 8 bf16 (rows 0..7). UP = up-neighbor at this col,
// DIAG = up-neighbor at col-1. Lr = values at col-1, Cw = this col. BOT = Cw[7].
#define COL(QV, UP, DIAG, Lr, Cw, BOT)                                  \
  do {                                                                  \
    float d0 = __uint_as_float((QV).x << 16);                           \
    float d1 = __uint_as_float((QV).x & 0xFFFF0000u);                   \
    float d2 = __uint_as_float((QV).y << 16);                           \
    float d3 = __uint_as_float((QV).y & 0xFFFF0000u);                   \
    float d4 = __uint_as_float((QV).z << 16);                           \
    float d5 = __uint_as_float((QV).z & 0xFFFF0000u);                   \
    float d6 = __uint_as_float((QV).w << 16);                           \
    float d7 = __uint_as_float((QV).w & 0xFFFF0000u);                   \
    Cw[0] = d0 + fminf(fminf(Lr[0], (DIAG)), (UP));                     \
    Cw[1] = d1 + fminf(fminf(Lr[1], Lr[0]), Cw[0]);                     \
    Cw[2] = d2 + fminf(fminf(Lr[2], Lr[1]), Cw[1]);                     \
    Cw[3] = d3 + fminf(fminf(Lr[3], Lr[2]), Cw[2]);                     \
    Cw[4] = d4 + fminf(fminf(Lr[4], Lr[3]), Cw[3]);                     \
    Cw[5] = d5 + fminf(fminf(Lr[5], Lr[4]), Cw[4]);                     \
    Cw[6] = d6 + fminf(fminf(Lr[6], Lr[5]), Cw[5]);                     \
    Cw[7] = d7 + fminf(fminf(Lr[7], Lr[6]), Cw[6]);                     \
    BOT = Cw[7];                                                        \
  } while (0)

// Order inside a supertick: read nb -> compute 4 COLs from pf[K] -> publish
// bottoms -> THEN refill pf[K] for t+4 (must come after the COLs: round-3 bug
// was refilling first, clobbering the current columns). End with lgkm drain +
// raw barrier; vmcnt left outstanding on purpose.
#define SUPER(K)                                                        \
  do {                                                                  \
    float4 nb = lbuf[(K) & 1][Lg];                                      \
    float b0, b1, b2, b3;                                               \
    COL(pf[K][0], nb.x, topPrev, pa, pb, b0);                           \
    COL(pf[K][1], nb.y, nb.x, pb, pa, b1);                              \
    COL(pf[K][2], nb.z, nb.y, pa, pb, b2);                              \
    COL(pf[K][3], nb.w, nb.z, pb, pa, b3);                              \
    topPrev = nb.w;                                                     \
    lbuf[((K) + 1) & 1][Lg + 1] = make_float4(b0, b1, b2, b3);          \
    { /* refill slot K for supertick t+4 */                             \
      _Pragma("unroll") for (int ci = 0; ci < 4; ++ci) {                \
        unsigned c = (unsigned)(cbase + ci);                            \
        unsigned off = (c > (unsigned)(MM - 1)) ? infoff                \
                                                : (c << 12) + laneoff;  \
        pf[K][ci] = *(const uint4*)(dbp + off);                         \
      }                                                                 \
      cbase += 4;                                                       \
    }                                                                   \
    asm volatile("s_waitcnt lgkmcnt(0)" ::: "memory");                  \
    __builtin_amdgcn_s_barrier();                                       \
    asm volatile("" ::: "memory");                                      \
  } while (0)

__global__ __launch_bounds__(256) void dp_k(const bf16* __restrict__ dist,
                                            float* __restrict__ out) {
  const int b = blockIdx.x, Lg = threadIdx.x;
  __shared__ float4 lbuf[2][257];  // [parity][writer lane+1]; slot 0 = INF wall

  const float4 inf4 = make_float4(INF, INF, INF, INF);
  lbuf[0][Lg] = inf4;
  lbuf[1][Lg] = inf4;
  if (Lg == 0) { lbuf[0][256] = inf4; lbuf[1][256] = inf4; }

  const char* dbp = (const char*)(dist + (size_t)b * NN * MM);
  const unsigned laneoff = (unsigned)Lg * 16u;  // 8 rows * 2B
  const unsigned infoff = (unsigned)((size_t)(BB - b) * NN * MM * 2) + laneoff;

  uint4 pf[4][4];  // 4 superticks deep x 4 cols
#pragma unroll
  for (int k = 0; k < 4; ++k)
#pragma unroll
    for (int ci = 0; ci < 4; ++ci) {
      unsigned c = (unsigned)(4 * (k - Lg) + ci);
      unsigned off = (c > (unsigned)(MM - 1)) ? infoff : (c << 12) + laneoff;
      pf[k][ci] = *(const uint4*)(dbp + off);
    }

  float pa[8], pb[8];
#pragma unroll
  for (int r = 0; r < 8; ++r) { pa[r] = INF; pb[r] = INF; }
  float topPrev = (Lg == 0) ? 0.f : INF;  // makes cell (0,0) cand==0 fall out
  int cbase = 16 - 4 * Lg;                // col base for refill target t+4
  __syncthreads();

  // superticks t = 0..766; lane 255 computes col 2047 row 2047 at t=766.
  for (int tb = 0; tb < 191; ++tb) {  // t = 0..763
    SUPER(0);
    SUPER(1);
    SUPER(2);
    SUPER(3);
  }
  SUPER(0);  // t=764
  SUPER(1);  // t=765
  SUPER(2);  // t=766: col block 2044..2047 for lane 255; ends in pa
  if (Lg == 255) out[b] = pa[7];
}

extern "C" void kernel_launch(void* const* d_in, const int* in_sizes, int n_in,
                              void* d_out, int out_size, void* d_ws, size_t ws_size,
                              hipStream_t stream) {
  const float* X = (const float*)d_in[0];
  const float* Y = (const float*)d_in[1];
  float* out = (float*)d_out;

  float* x2 = (float*)d_ws;                         // BB*NN floats (64KB)
  float* y2 = x2 + BB * NN;                         // BB*MM floats (64KB)
  bf16* dist = (bf16*)((char*)d_ws + 131072);       // BB*NN*MM bf16, col-major
  unsigned* infpad = (unsigned*)(dist + (size_t)BB * NN * MM);  // 4KB INF

  norms_k<<<dim3((BB * NN + 255) / 256), dim3(256), 0, stream>>>(X, x2, BB * NN);
  norms_k<<<dim3((BB * MM + 255) / 256), dim3(256), 0, stream>>>(Y, y2, BB * MM);
  fillinf_k<<<dim3(4), dim3(256), 0, stream>>>(infpad);

  dist_k<<<dim3(MM / 64, NN / 64, BB), dim3(256), 0, stream>>>(X, Y, x2, y2, dist);
  dp_k<<<dim3(BB), dim3(256), 0, stream>>>(dist, out);
}